// Round 5
// baseline (389.737 us; speedup 1.0000x reference)
//
#include <hip/hip_runtime.h>
#include <hip/hip_bf16.h>
#include <stdint.h>

// Problem: B=4, T_p=T_f=16, S=256, D=2048, H=16, hd=128, T=64 tokens.
// Inputs f32; outputs f32. GEMMs in bf16 MFMA (f32 accumulate); RoPE fused
// into the qkv GEMM epilogue (BN=128 => rotation partner is in-thread).

using bf16x8v = __attribute__((ext_vector_type(8))) __bf16;
using f32x4v  = __attribute__((ext_vector_type(4))) float;

union Pack8 { __bf16 h[8]; uint4 u; };

// XOR-swizzled element offset in a [R rows][64 bf16] LDS tile:
// row stride 64 el (128B), 8 chunks of 8 el; chunk c lives at c^(row&7).
__device__ __forceinline__ int swz(int r, int c) {
    return (r << 6) + ((c ^ (r & 7)) << 3);
}

// ---------------------------------------------------------------------------
// 0) Transpose + convert both weights: f32 [2048][N] -> bf16 [N][2048].
// grid 4096: bid<3072 -> W_qkv (N=6144); else W_proj (N=2048).
__global__ __launch_bounds__(256) void prep_w_kernel(
    const float* __restrict__ W_qkv, const float* __restrict__ W_proj,
    __bf16* __restrict__ Wt_qkv, __bf16* __restrict__ Wt_proj)
{
    int bid = blockIdx.x;
    const float* src; __bf16* dst; int N, tile;
    if (bid < 3072) { src = W_qkv;  dst = Wt_qkv;  N = 6144; tile = bid; }
    else            { src = W_proj; dst = Wt_proj; N = 2048; tile = bid - 3072; }
    __shared__ float Ls[64][68];
    int tiles_n = N >> 6;
    int tn = tile % tiles_n;
    int tk = tile / tiles_n;
    int t = threadIdx.x;
    int rb = t >> 4;            // 0..15
    int c4 = (t & 15) << 2;     // 0..60
    #pragma unroll
    for (int s = 0; s < 4; ++s) {
        int r = rb + (s << 4);
        float4 v = *reinterpret_cast<const float4*>(
            src + (size_t)(tk * 64 + r) * N + tn * 64 + c4);
        *reinterpret_cast<float4*>(&Ls[r][c4]) = v;
    }
    __syncthreads();
    int c  = t >> 2;            // 0..63
    int r0 = (t & 3) << 4;      // 0,16,32,48
    Pack8 p0, p1;
    #pragma unroll
    for (int i = 0; i < 8; ++i) p0.h[i] = (__bf16)Ls[r0 + i][c];
    #pragma unroll
    for (int i = 0; i < 8; ++i) p1.h[i] = (__bf16)Ls[r0 + 8 + i][c];
    __bf16* drow = dst + (size_t)(tn * 64 + c) * 2048 + tk * 64 + r0;
    *reinterpret_cast<uint4*>(drow)     = p0.u;
    *reinterpret_cast<uint4*>(drow + 8) = p1.u;
}

// ---------------------------------------------------------------------------
// 1a) mean stage 1: partial sums over s-chunks of 32. grid 2048 x 256.
__global__ __launch_bounds__(256) void mean_stage1_kernel(
    const float* __restrict__ v_p, const float* __restrict__ v_f,
    float* __restrict__ partials)
{
    int bid = blockIdx.x;
    int which  = bid >> 10;         // 0: v_p, 1: v_f
    int rem    = bid & 1023;
    int row    = rem >> 4;          // 0..63 = b*16+t
    int dchunk = (rem >> 3) & 1;
    int schunk = rem & 7;
    int d = (dchunk << 10) + (threadIdx.x << 2);
    const float* src = (which ? v_f : v_p) + ((size_t)row << 19)
                     + ((size_t)(schunk << 5) << 11) + d;
    float4 a = {0.f, 0.f, 0.f, 0.f};
    #pragma unroll 8
    for (int s = 0; s < 32; ++s) {
        float4 x = *reinterpret_cast<const float4*>(src + ((size_t)s << 11));
        a.x += x.x; a.y += x.y; a.z += x.z; a.w += x.w;
    }
    int pr = which * 64 + row;
    *reinterpret_cast<float4*>(&partials[(size_t)((pr << 3) + schunk) * 2048 + d]) = a;
}

// 1b) finish tokens: blocks 0..127 reduce means -> rows 0..31/batch;
//     blocks 128..255 pack audio -> rows 32..63/batch. tokens_bf out.
__global__ __launch_bounds__(256) void tokens_finish_kernel(
    const float* __restrict__ partials, const float* __restrict__ a_p,
    const float* __restrict__ a_f, __bf16* __restrict__ tokens_bf)
{
    int bid = blockIdx.x;
    if (bid < 128) {
        int idx = (bid * 256 + threadIdx.x) * 8;   // 0..262143
        int r = idx >> 11;            // 0..127 = which*64 + b*16+tt
        int d = idx & 2047;
        float s[8];
        #pragma unroll
        for (int i = 0; i < 8; ++i) s[i] = 0.f;
        #pragma unroll
        for (int sc = 0; sc < 8; ++sc) {
            const float* p = partials + (size_t)((r << 3) + sc) * 2048 + d;
            float4 x0 = *reinterpret_cast<const float4*>(p);
            float4 x1 = *reinterpret_cast<const float4*>(p + 4);
            s[0] += x0.x; s[1] += x0.y; s[2] += x0.z; s[3] += x0.w;
            s[4] += x1.x; s[5] += x1.y; s[6] += x1.z; s[7] += x1.w;
        }
        const float inv = 1.f / 256.f;
        int which = r >> 6, rr = r & 63;
        int b = rr >> 4, tt = rr & 15;
        int tokrow = b * 64 + which * 16 + tt;
        Pack8 p;
        #pragma unroll
        for (int i = 0; i < 8; ++i) p.h[i] = (__bf16)(s[i] * inv);
        *reinterpret_cast<uint4*>(&tokens_bf[(size_t)tokrow * 2048 + d]) = p.u;
    } else {
        int g = (bid - 128) * 256 + threadIdx.x;   // 8-elem group, 0..32767
        int which = g >> 14;
        int j = g & 16383;
        int b = j >> 12;
        int rr = j & 4095;
        int tt = rr >> 8;
        int gq = rr & 255;
        const float* src = (which ? a_f : a_p) + (size_t)(b * 16 + tt) * 2048 + gq * 8;
        float4 x0 = *reinterpret_cast<const float4*>(src);
        float4 x1 = *reinterpret_cast<const float4*>(src + 4);
        Pack8 p;
        p.h[0] = (__bf16)x0.x; p.h[1] = (__bf16)x0.y; p.h[2] = (__bf16)x0.z; p.h[3] = (__bf16)x0.w;
        p.h[4] = (__bf16)x1.x; p.h[5] = (__bf16)x1.y; p.h[6] = (__bf16)x1.z; p.h[7] = (__bf16)x1.w;
        int tokrow = b * 64 + 32 + which * 16 + tt;
        *reinterpret_cast<uint4*>(&tokens_bf[(size_t)tokrow * 2048 + gq * 8]) = p.u;
    }
}

// ---------------------------------------------------------------------------
// 2) bf16 MFMA GEMM: C[64*grid.y][N] = A * Bt^T (+bias), optional fused RoPE.
// Tile 64 x BN, BK=64, 4 waves; wave w: rows 16w..16w+15 x BN cols.
// ROPE requires BN=128 (rotation partner acc[j^4] is in-thread).
template<int BN, bool ROPE>
__global__ __launch_bounds__(256) void gemm_bf16_kernel(
    const __bf16* __restrict__ A, const __bf16* __restrict__ Bt,
    const float* __restrict__ bias, float* __restrict__ C, int N)
{
    constexpr int NJ = BN / 16;
    constexpr int NR = BN / 32;
    __shared__ __bf16 As[4096];
    __shared__ __bf16 Bs[BN * 64];
    const int t = threadIdx.x;
    const int m0 = blockIdx.y << 6;
    const int n0 = blockIdx.x * BN;
    const int lane = t & 63;
    const int wm = (t >> 6) << 4;
    const int lrow = lane & 15;
    const int lk = lane >> 4;            // 0..3
    const int srow = t >> 3;             // 0..31
    const int sc = t & 7;
    const __bf16* gA = A  + (size_t)(m0 + srow) * 2048 + (sc << 3);
    const __bf16* gB = Bt + (size_t)(n0 + srow) * 2048 + (sc << 3);

    f32x4v acc[NJ];
    #pragma unroll
    for (int j = 0; j < NJ; ++j) acc[j] = {0.f, 0.f, 0.f, 0.f};

    uint4 pa[2], pb[NR];
    pa[0] = *reinterpret_cast<const uint4*>(gA);
    pa[1] = *reinterpret_cast<const uint4*>(gA + 32 * 2048);
    #pragma unroll
    for (int r = 0; r < NR; ++r)
        pb[r] = *reinterpret_cast<const uint4*>(gB + (size_t)(r * 32) * 2048);

    for (int kt = 0; kt < 32; ++kt) {
        __syncthreads();
        *reinterpret_cast<uint4*>(&As[swz(srow, sc)])      = pa[0];
        *reinterpret_cast<uint4*>(&As[swz(srow + 32, sc)]) = pa[1];
        #pragma unroll
        for (int r = 0; r < NR; ++r)
            *reinterpret_cast<uint4*>(&Bs[swz(srow + r * 32, sc)]) = pb[r];
        __syncthreads();
        if (kt < 31) {
            const __bf16* nA = gA + (kt + 1) * 64;
            const __bf16* nB = gB + (kt + 1) * 64;
            pa[0] = *reinterpret_cast<const uint4*>(nA);
            pa[1] = *reinterpret_cast<const uint4*>(nA + 32 * 2048);
            #pragma unroll
            for (int r = 0; r < NR; ++r)
                pb[r] = *reinterpret_cast<const uint4*>(nB + (size_t)(r * 32) * 2048);
        }
        #pragma unroll
        for (int s = 0; s < 2; ++s) {
            int cA = (s << 2) + lk;
            bf16x8v af = *reinterpret_cast<const bf16x8v*>(&As[swz(wm + lrow, cA)]);
            #pragma unroll
            for (int j = 0; j < NJ; ++j) {
                bf16x8v bf = *reinterpret_cast<const bf16x8v*>(&Bs[swz((j << 4) + lrow, cA)]);
                acc[j] = __builtin_amdgcn_mfma_f32_16x16x32_bf16(af, bf, acc[j], 0, 0, 0);
            }
        }
    }
    // fused RoPE on q,k tiles (n0 < 4096); head dim d = j*16+lrow (n0 128-aligned)
    if (ROPE && n0 < 4096) {
        const float l2 = 0.20762050593046012f;   // log2(10000)/64
        #pragma unroll
        for (int j = 0; j < 4; ++j) {
            int dd = (j << 4) + lrow;            // 0..63
            float invf = exp2f(-(float)dd * l2);
            #pragma unroll
            for (int e = 0; e < 4; ++e) {
                int row = m0 + wm + (lk << 2) + e;
                float ang = (float)(row & 63) * invf;
                float cc = cosf(ang), ss = sinf(ang);
                float x1 = acc[j][e], x2 = acc[j + 4][e];
                acc[j][e]     = x1 * cc - x2 * ss;
                acc[j + 4][e] = x2 * cc + x1 * ss;
            }
        }
    }
    // epilogue: C/D layout col=lane&15, row=(lane>>4)*4+reg
    #pragma unroll
    for (int j = 0; j < NJ; ++j) {
        int col = n0 + (j << 4) + lrow;
        float bv = bias ? bias[col] : 0.f;
        #pragma unroll
        for (int e = 0; e < 4; ++e) {
            int row = m0 + wm + (lk << 2) + e;
            C[(size_t)row * N + col] = acc[j][e] + bv;
        }
    }
}

// ---------------------------------------------------------------------------
// 3) Attention: block = (b, h, q-half of 32 rows). grid 128 x 256.
// Thread (qi=tid>>3 local, g=tid&7): 8 score cols (ki=8j+g), 16 out dims.
__global__ __launch_bounds__(256) void attn_kernel(
    const float* __restrict__ qkv, __bf16* __restrict__ attn_out)
{
    __shared__ float q_s[32 * 128];   // 16KB; reused as p_s[32][65]
    __shared__ float k_s[64 * 128];   // 32KB
    __shared__ float v_s[64 * 128];   // 32KB
    int bid = blockIdx.x;
    int qt = bid & 1;
    int h  = (bid >> 1) & 15;
    int b  = bid >> 5;
    int tid = threadIdx.x;
    const float* base = qkv + (size_t)(b * 64) * 6144 + h * 128;
    int qr0 = qt << 5;
    int kcap = qr0 + 32;              // causal: rows beyond q-tile never used
    #pragma unroll
    for (int r = 0; r < 4; ++r) {
        int idx = tid + (r << 8);
        int tq = idx >> 5;            // 0..31
        int d = (idx & 31) << 2;
        *reinterpret_cast<float4*>(&q_s[tq * 128 + d]) =
            *reinterpret_cast<const float4*>(base + (size_t)(qr0 + tq) * 6144 + d);
    }
    for (int idx = tid; idx < (kcap << 5); idx += 256) {
        int tk = idx >> 5;
        int d = (idx & 31) << 2;
        const float* srck = base + (size_t)tk * 6144 + 2048 + d;
        *reinterpret_cast<float4*>(&k_s[tk * 128 + d]) = *reinterpret_cast<const float4*>(srck);
        *reinterpret_cast<float4*>(&v_s[tk * 128 + d]) = *reinterpret_cast<const float4*>(srck + 2048);
    }
    __syncthreads();
    int qi = tid >> 3;                // 0..31 local
    int g  = tid & 7;
    int qg = qr0 + qi;                // global q row
    int nj = kcap >> 3;               // 4 or 8
    float pv[8];
    #pragma unroll
    for (int j = 0; j < 8; ++j) pv[j] = 0.f;
    for (int d = 0; d < 128; d += 4) {
        float4 a = *reinterpret_cast<const float4*>(&q_s[qi * 128 + d]);
        for (int j = 0; j < nj; ++j) {
            int ki = (j << 3) + g;
            float4 bb = *reinterpret_cast<const float4*>(&k_s[ki * 128 + d]);
            pv[j] += a.x * bb.x + a.y * bb.y + a.z * bb.z + a.w * bb.w;
        }
    }
    const float scale = 0.0883883476483184405f;   // 128^-0.5
    float m = -1e30f;
    for (int j = 0; j < nj; ++j) {
        int ki = (j << 3) + g;
        pv[j] = (ki <= qg) ? pv[j] * scale : -1e30f;
        m = fmaxf(m, pv[j]);
    }
    m = fmaxf(m, __shfl_xor(m, 1));
    m = fmaxf(m, __shfl_xor(m, 2));
    m = fmaxf(m, __shfl_xor(m, 4));
    float l = 0.f;
    for (int j = 0; j < nj; ++j) {
        float e = (pv[j] > -1e29f) ? expf(pv[j] - m) : 0.f;
        pv[j] = e;
        l += e;
    }
    l += __shfl_xor(l, 1);
    l += __shfl_xor(l, 2);
    l += __shfl_xor(l, 4);
    float inv_l = 1.f / l;
    __syncthreads();                  // done reading q_s
    float* p_s = q_s;                 // [32][65]
    for (int j = 0; j < nj; ++j) p_s[qi * 65 + (j << 3) + g] = pv[j] * inv_l;
    __syncthreads();
    int d0 = g << 4;
    float4 acc[4];
    #pragma unroll
    for (int u = 0; u < 4; ++u) acc[u] = {0.f, 0.f, 0.f, 0.f};
    for (int ki = 0; ki < kcap; ++ki) {
        float p = p_s[qi * 65 + ki];
        #pragma unroll
        for (int u = 0; u < 4; ++u) {
            float4 vv = *reinterpret_cast<const float4*>(&v_s[ki * 128 + d0 + (u << 2)]);
            acc[u].x += p * vv.x;
            acc[u].y += p * vv.y;
            acc[u].z += p * vv.z;
            acc[u].w += p * vv.w;
        }
    }
    __bf16* orow = attn_out + (size_t)(b * 64 + qg) * 2048 + h * 128 + d0;
    #pragma unroll
    for (int v = 0; v < 2; ++v) {
        Pack8 p;
        float4 a0 = acc[2 * v], a1 = acc[2 * v + 1];
        p.h[0] = (__bf16)a0.x; p.h[1] = (__bf16)a0.y; p.h[2] = (__bf16)a0.z; p.h[3] = (__bf16)a0.w;
        p.h[4] = (__bf16)a1.x; p.h[5] = (__bf16)a1.y; p.h[6] = (__bf16)a1.z; p.h[7] = (__bf16)a1.w;
        *reinterpret_cast<uint4*>(orow + v * 8) = p.u;
    }
}

// ---------------------------------------------------------------------------
// 4) Outputs: blocks 0..2047 broadcast video; 2048..2175 copy audio. f32.
__global__ __launch_bounds__(256) void outputs_kernel(
    const float* __restrict__ outp, float* __restrict__ d_out)
{
    int bid = blockIdx.x;
    if (bid < 2048) {
        int which = bid >> 10;
        int rem = bid & 1023;
        int row = rem >> 4;             // b*16 + t
        int schunk = rem & 15;
        int b = row >> 4;
        int t = row & 15;
        const float* src = outp + (size_t)(b * 64 + (which << 4) + t) * 2048 + threadIdx.x * 8;
        float4 o0 = *reinterpret_cast<const float4*>(src);
        float4 o1 = *reinterpret_cast<const float4*>(src + 4);
        size_t base = (size_t)which * 33554432 +
                      ((size_t)row * 256 + (size_t)schunk * 16) * 2048 + threadIdx.x * 8;
        float* dst = d_out + base;
        #pragma unroll
        for (int s = 0; s < 16; ++s) {
            *reinterpret_cast<float4*>(dst + (size_t)s * 2048)     = o0;
            *reinterpret_cast<float4*>(dst + (size_t)s * 2048 + 4) = o1;
        }
    } else {
        int g = (bid - 2048) * 256 + threadIdx.x;   // 8-float group, 0..32767
        int which = g >> 14;
        int j = g & 16383;
        int b = j >> 12;
        int rr = j & 4095;
        int tt = rr >> 8;
        int gq = rr & 255;
        const float* src = outp + (size_t)(b * 64 + 32 + (which << 4) + tt) * 2048 + gq * 8;
        float4 x0 = *reinterpret_cast<const float4*>(src);
        float4 x1 = *reinterpret_cast<const float4*>(src + 4);
        float* dst = d_out + 67108864 + (size_t)which * 131072 +
                     (size_t)(b * 16 + tt) * 2048 + gq * 8;
        *reinterpret_cast<float4*>(dst)     = x0;
        *reinterpret_cast<float4*>(dst + 4) = x1;
    }
}

// ---------------------------------------------------------------------------
extern "C" void kernel_launch(void* const* d_in, const int* in_sizes, int n_in,
                              void* d_out, int out_size, void* d_ws, size_t ws_size,
                              hipStream_t stream)
{
    const float* v_p    = (const float*)d_in[0];
    const float* v_f    = (const float*)d_in[1];
    const float* a_p    = (const float*)d_in[2];
    const float* a_f    = (const float*)d_in[3];
    const float* W_qkv  = (const float*)d_in[4];
    const float* W_proj = (const float*)d_in[5];
    const float* b_proj = (const float*)d_in[6];
    float* out_f = (float*)d_out;

    char* ws = (char*)d_ws;
    __bf16* tokens_bf = (__bf16*)(ws);                       // 1 MB
    __bf16* Wt_qkv    = (__bf16*)(ws + 1048576);             // 24 MB
    __bf16* Wt_proj   = (__bf16*)(ws + 26214400);            // 8 MB
    float*  qkv       = (float*)(ws + 34603008);             // 6 MB
    __bf16* attn_bf   = (__bf16*)(ws + 40894464);            // 1 MB
    float*  outp      = (float*)(ws + 41943040);             // 2 MB
    float*  partials  = (float*)(ws + 44040192);             // 8 MB

    prep_w_kernel<<<4096, 256, 0, stream>>>(W_qkv, W_proj, Wt_qkv, Wt_proj);
    mean_stage1_kernel<<<2048, 256, 0, stream>>>(v_p, v_f, partials);
    tokens_finish_kernel<<<256, 256, 0, stream>>>(partials, a_p, a_f, tokens_bf);
    gemm_bf16_kernel<128, true><<<dim3(48, 4), 256, 0, stream>>>(tokens_bf, Wt_qkv, nullptr, qkv, 6144);
    attn_kernel<<<128, 256, 0, stream>>>(qkv, attn_bf);
    gemm_bf16_kernel<64, false><<<dim3(32, 4), 256, 0, stream>>>(attn_bf, Wt_proj, b_proj, outp, 2048);
    outputs_kernel<<<2176, 256, 0, stream>>>(outp, out_f);
}

// Round 6
// 241.093 us; speedup vs baseline: 1.6165x; 1.6165x over previous
//
#include <hip/hip_runtime.h>
#include <hip/hip_bf16.h>
#include <stdint.h>

// Problem: B=4, T_p=T_f=16, S=256, D=2048, H=16, hd=128, T=64 tokens.
// Inputs f32; outputs f32. GEMMs in bf16 MFMA (f32 accumulate).
// R6 = R4's verified gemm64/rope/attn + R5's safe launch fusions (bisect).

using bf16x8v = __attribute__((ext_vector_type(8))) __bf16;
using f32x4v  = __attribute__((ext_vector_type(4))) float;

union Pack8 { __bf16 h[8]; uint4 u; };

// XOR-swizzled element offset in a [64 rows][64 bf16] LDS tile:
// row stride 64 el (128B), 8 chunks of 8 el; chunk c lives at c^(row&7).
__device__ __forceinline__ int swz(int r, int c) {
    return (r << 6) + ((c ^ (r & 7)) << 3);
}

// ---------------------------------------------------------------------------
// 0) Transpose + convert both weights: f32 [2048][N] -> bf16 [N][2048].
// grid 4096: bid<3072 -> W_qkv (N=6144); else W_proj (N=2048).
__global__ __launch_bounds__(256) void prep_w_kernel(
    const float* __restrict__ W_qkv, const float* __restrict__ W_proj,
    __bf16* __restrict__ Wt_qkv, __bf16* __restrict__ Wt_proj)
{
    int bid = blockIdx.x;
    const float* src; __bf16* dst; int N, tile;
    if (bid < 3072) { src = W_qkv;  dst = Wt_qkv;  N = 6144; tile = bid; }
    else            { src = W_proj; dst = Wt_proj; N = 2048; tile = bid - 3072; }
    __shared__ float Ls[64][68];
    int tiles_n = N >> 6;
    int tn = tile % tiles_n;
    int tk = tile / tiles_n;
    int t = threadIdx.x;
    int rb = t >> 4;            // 0..15
    int c4 = (t & 15) << 2;     // 0..60
    #pragma unroll
    for (int s = 0; s < 4; ++s) {
        int r = rb + (s << 4);
        float4 v = *reinterpret_cast<const float4*>(
            src + (size_t)(tk * 64 + r) * N + tn * 64 + c4);
        *reinterpret_cast<float4*>(&Ls[r][c4]) = v;
    }
    __syncthreads();
    int c  = t >> 2;            // 0..63
    int r0 = (t & 3) << 4;      // 0,16,32,48
    Pack8 p0, p1;
    #pragma unroll
    for (int i = 0; i < 8; ++i) p0.h[i] = (__bf16)Ls[r0 + i][c];
    #pragma unroll
    for (int i = 0; i < 8; ++i) p1.h[i] = (__bf16)Ls[r0 + 8 + i][c];
    __bf16* drow = dst + (size_t)(tn * 64 + c) * 2048 + tk * 64 + r0;
    *reinterpret_cast<uint4*>(drow)     = p0.u;
    *reinterpret_cast<uint4*>(drow + 8) = p1.u;
}

// ---------------------------------------------------------------------------
// 1a) mean stage 1: partial sums over s-chunks of 32. grid 2048 x 256.
__global__ __launch_bounds__(256) void mean_stage1_kernel(
    const float* __restrict__ v_p, const float* __restrict__ v_f,
    float* __restrict__ partials)
{
    int bid = blockIdx.x;
    int which  = bid >> 10;         // 0: v_p, 1: v_f
    int rem    = bid & 1023;
    int row    = rem >> 4;          // 0..63 = b*16+t
    int dchunk = (rem >> 3) & 1;
    int schunk = rem & 7;
    int d = (dchunk << 10) + (threadIdx.x << 2);
    const float* src = (which ? v_f : v_p) + ((size_t)row << 19)
                     + ((size_t)(schunk << 5) << 11) + d;
    float4 a = {0.f, 0.f, 0.f, 0.f};
    #pragma unroll 8
    for (int s = 0; s < 32; ++s) {
        float4 x = *reinterpret_cast<const float4*>(src + ((size_t)s << 11));
        a.x += x.x; a.y += x.y; a.z += x.z; a.w += x.w;
    }
    int pr = which * 64 + row;
    *reinterpret_cast<float4*>(&partials[(size_t)((pr << 3) + schunk) * 2048 + d]) = a;
}

// 1b) finish tokens: blocks 0..127 reduce means -> rows 0..31/batch;
//     blocks 128..255 pack audio -> rows 32..63/batch. tokens_bf out.
__global__ __launch_bounds__(256) void tokens_finish_kernel(
    const float* __restrict__ partials, const float* __restrict__ a_p,
    const float* __restrict__ a_f, __bf16* __restrict__ tokens_bf)
{
    int bid = blockIdx.x;
    if (bid < 128) {
        int idx = (bid * 256 + threadIdx.x) * 8;   // 0..262143
        int r = idx >> 11;            // 0..127 = which*64 + b*16+tt
        int d = idx & 2047;
        float s[8];
        #pragma unroll
        for (int i = 0; i < 8; ++i) s[i] = 0.f;
        #pragma unroll
        for (int sc = 0; sc < 8; ++sc) {
            const float* p = partials + (size_t)((r << 3) + sc) * 2048 + d;
            float4 x0 = *reinterpret_cast<const float4*>(p);
            float4 x1 = *reinterpret_cast<const float4*>(p + 4);
            s[0] += x0.x; s[1] += x0.y; s[2] += x0.z; s[3] += x0.w;
            s[4] += x1.x; s[5] += x1.y; s[6] += x1.z; s[7] += x1.w;
        }
        const float inv = 1.f / 256.f;
        int which = r >> 6, rr = r & 63;
        int b = rr >> 4, tt = rr & 15;
        int tokrow = b * 64 + which * 16 + tt;
        Pack8 p;
        #pragma unroll
        for (int i = 0; i < 8; ++i) p.h[i] = (__bf16)(s[i] * inv);
        *reinterpret_cast<uint4*>(&tokens_bf[(size_t)tokrow * 2048 + d]) = p.u;
    } else {
        int g = (bid - 128) * 256 + threadIdx.x;   // 8-elem group, 0..32767
        int which = g >> 14;
        int j = g & 16383;
        int b = j >> 12;
        int rr = j & 4095;
        int tt = rr >> 8;
        int gq = rr & 255;
        const float* src = (which ? a_f : a_p) + (size_t)(b * 16 + tt) * 2048 + gq * 8;
        float4 x0 = *reinterpret_cast<const float4*>(src);
        float4 x1 = *reinterpret_cast<const float4*>(src + 4);
        Pack8 p;
        p.h[0] = (__bf16)x0.x; p.h[1] = (__bf16)x0.y; p.h[2] = (__bf16)x0.z; p.h[3] = (__bf16)x0.w;
        p.h[4] = (__bf16)x1.x; p.h[5] = (__bf16)x1.y; p.h[6] = (__bf16)x1.z; p.h[7] = (__bf16)x1.w;
        int tokrow = b * 64 + 32 + which * 16 + tt;
        *reinterpret_cast<uint4*>(&tokens_bf[(size_t)tokrow * 2048 + gq * 8]) = p.u;
    }
}

// ---------------------------------------------------------------------------
// 2) bf16 MFMA GEMM (R4-verified): C[64g.y][N] = A * Bt^T (+bias).
// 64x64 tile, BK=64, 4 waves; wave w computes rows 16w..16w+15 x 64 cols.
__global__ __launch_bounds__(256) void gemm_bf16_kernel(
    const __bf16* __restrict__ A, const __bf16* __restrict__ Bt,
    const float* __restrict__ bias, float* __restrict__ C, int N)
{
    __shared__ __bf16 As[4096];
    __shared__ __bf16 Bs[4096];
    const int t = threadIdx.x;
    const int m0 = blockIdx.y << 6;
    const int n0 = blockIdx.x << 6;
    const int lane = t & 63;
    const int wm = (t >> 6) << 4;        // wave's m offset (0,16,32,48)
    const int lrow = lane & 15;
    const int lk = lane >> 4;            // 0..3
    const int srow = t >> 3;             // 0..31
    const int sc = t & 7;
    const __bf16* gA = A  + (size_t)(m0 + srow) * 2048 + (sc << 3);
    const __bf16* gB = Bt + (size_t)(n0 + srow) * 2048 + (sc << 3);
    const int wA0 = swz(srow, sc), wA1 = swz(srow + 32, sc);

    f32x4v acc[4] = {{0.f,0.f,0.f,0.f},{0.f,0.f,0.f,0.f},
                     {0.f,0.f,0.f,0.f},{0.f,0.f,0.f,0.f}};
    uint4 pa0, pa1, pb0, pb1;
    pa0 = *reinterpret_cast<const uint4*>(gA);
    pa1 = *reinterpret_cast<const uint4*>(gA + 32 * 2048);
    pb0 = *reinterpret_cast<const uint4*>(gB);
    pb1 = *reinterpret_cast<const uint4*>(gB + 32 * 2048);

    for (int kt = 0; kt < 32; ++kt) {
        __syncthreads();
        *reinterpret_cast<uint4*>(&As[wA0]) = pa0;
        *reinterpret_cast<uint4*>(&As[wA1]) = pa1;
        *reinterpret_cast<uint4*>(&Bs[wA0]) = pb0;
        *reinterpret_cast<uint4*>(&Bs[wA1]) = pb1;
        __syncthreads();
        if (kt < 31) {
            const __bf16* nA = gA + (kt + 1) * 64;
            const __bf16* nB = gB + (kt + 1) * 64;
            pa0 = *reinterpret_cast<const uint4*>(nA);
            pa1 = *reinterpret_cast<const uint4*>(nA + 32 * 2048);
            pb0 = *reinterpret_cast<const uint4*>(nB);
            pb1 = *reinterpret_cast<const uint4*>(nB + 32 * 2048);
        }
        #pragma unroll
        for (int s = 0; s < 2; ++s) {
            int cA = (s << 2) + lk;
            bf16x8v af = *reinterpret_cast<const bf16x8v*>(&As[swz(wm + lrow, cA)]);
            #pragma unroll
            for (int j = 0; j < 4; ++j) {
                bf16x8v bf = *reinterpret_cast<const bf16x8v*>(&Bs[swz((j << 4) + lrow, cA)]);
                acc[j] = __builtin_amdgcn_mfma_f32_16x16x32_bf16(af, bf, acc[j], 0, 0, 0);
            }
        }
    }
    // epilogue: C/D layout col=lane&15, row=(lane>>4)*4+reg
    #pragma unroll
    for (int j = 0; j < 4; ++j) {
        int col = n0 + (j << 4) + lrow;
        float bv = bias ? bias[col] : 0.f;
        #pragma unroll
        for (int e = 0; e < 4; ++e) {
            int row = m0 + wm + (lk << 2) + e;
            C[(size_t)row * N + col] = acc[j][e] + bv;
        }
    }
}

// ---------------------------------------------------------------------------
// 3) RoPE in-place on q,k halves of qkv (f32). grid 256 x 256.
__global__ __launch_bounds__(256) void rope_kernel(float* __restrict__ qkv)
{
    int row = blockIdx.x;      // b*64 + t
    int t = row & 63;
    float* q = qkv + (size_t)row * 6144;
    for (int i = threadIdx.x; i < 1024; i += 256) {
        int h = i >> 6;
        int d = i & 63;
        float invf = powf(10000.f, -(float)d * (1.f / 64.f));
        float ang = (float)t * invf;
        float c = cosf(ang), s = sinf(ang);
        int i0 = h * 128 + d;
        float q1 = q[i0], q2 = q[i0 + 64];
        q[i0]      = q1 * c - q2 * s;
        q[i0 + 64] = q2 * c + q1 * s;
        float* k = q + 2048;
        float k1 = k[i0], k2 = k[i0 + 64];
        k[i0]      = k1 * c - k2 * s;
        k[i0 + 64] = k2 * c + k1 * s;
    }
}

// ---------------------------------------------------------------------------
// 4) Attention per (b,h) (R4-verified); causal softmax; bf16 out.
__global__ __launch_bounds__(256) void attn_kernel(
    const float* __restrict__ qkv, __bf16* __restrict__ attn_out)
{
    __shared__ float q_s[64 * 128];   // reused as p_s[64][65]
    __shared__ float k_s[64 * 128];   // reused as v_s
    int b = blockIdx.x >> 4;
    int h = blockIdx.x & 15;
    int tid = threadIdx.x;
    const float* base = qkv + (size_t)(b * 64) * 6144 + h * 128;
    #pragma unroll
    for (int r = 0; r < 8; ++r) {
        int idx = tid + (r << 8);
        int t = idx >> 5;
        int d = (idx & 31) << 2;
        const float* src = base + (size_t)t * 6144 + d;
        *reinterpret_cast<float4*>(&q_s[t * 128 + d]) = *reinterpret_cast<const float4*>(src);
        *reinterpret_cast<float4*>(&k_s[t * 128 + d]) = *reinterpret_cast<const float4*>(src + 2048);
    }
    __syncthreads();
    int qi = tid >> 2;
    int g  = tid & 3;
    float pv[16];
    #pragma unroll
    for (int j = 0; j < 16; ++j) pv[j] = 0.f;
    for (int d = 0; d < 128; d += 4) {
        float4 a = *reinterpret_cast<const float4*>(&q_s[qi * 128 + d]);
        #pragma unroll
        for (int j = 0; j < 16; ++j) {
            int ki = (j << 2) + g;
            float4 bb = *reinterpret_cast<const float4*>(&k_s[ki * 128 + d]);
            pv[j] += a.x * bb.x + a.y * bb.y + a.z * bb.z + a.w * bb.w;
        }
    }
    const float scale = 0.0883883476483184405f;   // 128^-0.5
    float m = -1e30f;
    #pragma unroll
    for (int j = 0; j < 16; ++j) {
        int ki = (j << 2) + g;
        pv[j] = (ki <= qi) ? pv[j] * scale : -1e30f;
        m = fmaxf(m, pv[j]);
    }
    m = fmaxf(m, __shfl_xor(m, 1));
    m = fmaxf(m, __shfl_xor(m, 2));
    float l = 0.f;
    #pragma unroll
    for (int j = 0; j < 16; ++j) {
        float e = (pv[j] > -1e29f) ? expf(pv[j] - m) : 0.f;
        pv[j] = e;
        l += e;
    }
    l += __shfl_xor(l, 1);
    l += __shfl_xor(l, 2);
    float inv_l = 1.f / l;
    __syncthreads();
    float* p_s = q_s;
    #pragma unroll
    for (int j = 0; j < 16; ++j) p_s[qi * 65 + (j << 2) + g] = pv[j] * inv_l;
    float* v_s = k_s;
    #pragma unroll
    for (int r = 0; r < 8; ++r) {
        int idx = tid + (r << 8);
        int t = idx >> 5;
        int d = (idx & 31) << 2;
        *reinterpret_cast<float4*>(&v_s[t * 128 + d]) =
            *reinterpret_cast<const float4*>(base + (size_t)t * 6144 + 4096 + d);
    }
    __syncthreads();
    int d0 = g << 5;
    float4 acc[8];
    #pragma unroll
    for (int u = 0; u < 8; ++u) acc[u] = {0.f, 0.f, 0.f, 0.f};
    for (int ki = 0; ki < 64; ++ki) {
        float p = p_s[qi * 65 + ki];
        #pragma unroll
        for (int u = 0; u < 8; ++u) {
            float4 vv = *reinterpret_cast<const float4*>(&v_s[ki * 128 + d0 + (u << 2)]);
            acc[u].x += p * vv.x;
            acc[u].y += p * vv.y;
            acc[u].z += p * vv.z;
            acc[u].w += p * vv.w;
        }
    }
    __bf16* orow = attn_out + (size_t)(b * 64 + qi) * 2048 + h * 128 + d0;
    #pragma unroll
    for (int v = 0; v < 4; ++v) {
        Pack8 p;
        float4 a0 = acc[2 * v], a1 = acc[2 * v + 1];
        p.h[0] = (__bf16)a0.x; p.h[1] = (__bf16)a0.y; p.h[2] = (__bf16)a0.z; p.h[3] = (__bf16)a0.w;
        p.h[4] = (__bf16)a1.x; p.h[5] = (__bf16)a1.y; p.h[6] = (__bf16)a1.z; p.h[7] = (__bf16)a1.w;
        *reinterpret_cast<uint4*>(orow + v * 8) = p.u;
    }
}

// ---------------------------------------------------------------------------
// 5) Outputs: blocks 0..2047 broadcast video; 2048..2175 copy audio. f32.
__global__ __launch_bounds__(256) void outputs_kernel(
    const float* __restrict__ outp, float* __restrict__ d_out)
{
    int bid = blockIdx.x;
    if (bid < 2048) {
        int which = bid >> 10;
        int rem = bid & 1023;
        int row = rem >> 4;             // b*16 + t
        int schunk = rem & 15;
        int b = row >> 4;
        int t = row & 15;
        const float* src = outp + (size_t)(b * 64 + (which << 4) + t) * 2048 + threadIdx.x * 8;
        float4 o0 = *reinterpret_cast<const float4*>(src);
        float4 o1 = *reinterpret_cast<const float4*>(src + 4);
        size_t base = (size_t)which * 33554432 +
                      ((size_t)row * 256 + (size_t)schunk * 16) * 2048 + threadIdx.x * 8;
        float* dst = d_out + base;
        #pragma unroll
        for (int s = 0; s < 16; ++s) {
            *reinterpret_cast<float4*>(dst + (size_t)s * 2048)     = o0;
            *reinterpret_cast<float4*>(dst + (size_t)s * 2048 + 4) = o1;
        }
    } else {
        int g = (bid - 2048) * 256 + threadIdx.x;   // 8-float group, 0..32767
        int which = g >> 14;
        int j = g & 16383;
        int b = j >> 12;
        int rr = j & 4095;
        int tt = rr >> 8;
        int gq = rr & 255;
        const float* src = outp + (size_t)(b * 64 + 32 + (which << 4) + tt) * 2048 + gq * 8;
        float4 x0 = *reinterpret_cast<const float4*>(src);
        float4 x1 = *reinterpret_cast<const float4*>(src + 4);
        float* dst = d_out + 67108864 + (size_t)which * 131072 +
                     (size_t)(b * 16 + tt) * 2048 + gq * 8;
        *reinterpret_cast<float4*>(dst)     = x0;
        *reinterpret_cast<float4*>(dst + 4) = x1;
    }
}

// ---------------------------------------------------------------------------
extern "C" void kernel_launch(void* const* d_in, const int* in_sizes, int n_in,
                              void* d_out, int out_size, void* d_ws, size_t ws_size,
                              hipStream_t stream)
{
    const float* v_p    = (const float*)d_in[0];
    const float* v_f    = (const float*)d_in[1];
    const float* a_p    = (const float*)d_in[2];
    const float* a_f    = (const float*)d_in[3];
    const float* W_qkv  = (const float*)d_in[4];
    const float* W_proj = (const float*)d_in[5];
    const float* b_proj = (const float*)d_in[6];
    float* out_f = (float*)d_out;

    char* ws = (char*)d_ws;
    __bf16* tokens_bf = (__bf16*)(ws);                       // 1 MB
    __bf16* Wt_qkv    = (__bf16*)(ws + 1048576);             // 24 MB
    __bf16* Wt_proj   = (__bf16*)(ws + 26214400);            // 8 MB
    float*  qkv       = (float*)(ws + 34603008);             // 6 MB
    __bf16* attn_bf   = (__bf16*)(ws + 40894464);            // 1 MB
    float*  outp      = (float*)(ws + 41943040);             // 2 MB
    float*  partials  = (float*)(ws + 44040192);             // 8 MB

    prep_w_kernel<<<4096, 256, 0, stream>>>(W_qkv, W_proj, Wt_qkv, Wt_proj);
    mean_stage1_kernel<<<2048, 256, 0, stream>>>(v_p, v_f, partials);
    tokens_finish_kernel<<<256, 256, 0, stream>>>(partials, a_p, a_f, tokens_bf);
    gemm_bf16_kernel<<<dim3(96, 4), 256, 0, stream>>>(tokens_bf, Wt_qkv, nullptr, qkv, 6144);
    rope_kernel<<<256, 256, 0, stream>>>(qkv);
    attn_kernel<<<64, 256, 0, stream>>>(qkv, attn_bf);
    gemm_bf16_kernel<<<dim3(32, 4), 256, 0, stream>>>(attn_bf, Wt_proj, b_proj, outp, 2048);
    outputs_kernel<<<2176, 256, 0, stream>>>(outp, out_f);
}